// Round 7
// baseline (356.523 us; speedup 1.0000x reference)
//
#include <hip/hip_runtime.h>
#include <cstdint>
#include <cmath>

// Problem constants
#define NB 2
#define NC 256
#define HW 2304          // 48*48
#define HID 64
#define OH 96
#define OW 96
#define N1 9216          // 96*96
#define SCALE_ATTN 0.17677669529663689f   // 32^-0.5
#define RESZ ((float)(47.0/95.0))

// ---------------- KA: weight prep. WT4[c4][128][4]; wT2[k=ic*9+tap][18]; dwT[tap][32]
__global__ void kA_prep(const float* __restrict__ Wq, const float* __restrict__ Wk,
                        const float* __restrict__ off_w, const float* __restrict__ dw_w,
                        float* __restrict__ WT4, float* __restrict__ wT2,
                        float* __restrict__ dwT) {
    int idx = blockIdx.x * 256 + threadIdx.x;
    if (idx < 256 * 128) {
        int c = idx >> 7, t = idx & 127;
        float v = (t < 64) ? Wq[t * 256 + c] : Wk[(t - 64) * 256 + c];
        WT4[(((size_t)(c >> 2) * 128) + t) * 4 + (c & 3)] = v;
    } else if (idx < 256 * 128 + 288 * 18) {
        int i = idx - 256 * 128;
        wT2[i] = off_w[(i % 18) * 288 + (i / 18)];
    } else if (idx < 256 * 128 + 288 * 18 + 288) {
        int i = idx - (256 * 128 + 288 * 18);
        int wi = i >> 5, c = i & 31;
        dwT[i] = dw_w[c * 9 + wi];
    }
}

// ---------------- K1: channel LN over 256 + Q/K projection, reading x directly.
// Block = 256 thr = 4 pixels (1 wave each). LN via 64-lane shfl butterfly.
__global__ __launch_bounds__(256) void k1_ln_qk(const float* __restrict__ x,
                         const float* __restrict__ ln_g, const float* __restrict__ ln_b,
                         const float* __restrict__ WT4,
                         float* __restrict__ q_pix, float* __restrict__ k_nhwc) {
    int blk = blockIdx.x;            // 0..1151
    int tid = threadIdx.x;
    int wv = tid >> 6, lane = tid & 63;
    __shared__ float xs[4][256];
    {
        int pix = blk * 4 + wv;
        int b = pix / HW, p = pix - b * HW;
        const float* xb = x + (size_t)b * NC * HW + p;
        float v0 = xb[(size_t)lane * HW];
        float v1 = xb[(size_t)(lane + 64) * HW];
        float v2 = xb[(size_t)(lane + 128) * HW];
        float v3 = xb[(size_t)(lane + 192) * HW];
        float s = v0 + v1 + v2 + v3;
#pragma unroll
        for (int off = 1; off < 64; off <<= 1) s += __shfl_xor(s, off);
        float mu = s * (1.f / 256.f);
        float d0 = v0 - mu, d1 = v1 - mu, d2 = v2 - mu, d3 = v3 - mu;
        float q = d0 * d0 + d1 * d1 + d2 * d2 + d3 * d3;
#pragma unroll
        for (int off = 1; off < 64; off <<= 1) q += __shfl_xor(q, off);
        float rs = rsqrtf(q * (1.f / 256.f) + 1e-5f);
        xs[wv][lane]       = d0 * rs * ln_g[lane]       + ln_b[lane];
        xs[wv][lane + 64]  = d1 * rs * ln_g[lane + 64]  + ln_b[lane + 64];
        xs[wv][lane + 128] = d2 * rs * ln_g[lane + 128] + ln_b[lane + 128];
        xs[wv][lane + 192] = d3 * rs * ln_g[lane + 192] + ln_b[lane + 192];
    }
    __syncthreads();
    int o = tid & 127, ph = tid >> 7;
    float a0 = 0.f, a1 = 0.f;
    const float4* wp = (const float4*)WT4 + o;         // stride 128 float4s per c4
    const float4* xa = (const float4*)xs[ph * 2];
    const float4* xb4 = (const float4*)xs[ph * 2 + 1];
#pragma unroll 8
    for (int c4 = 0; c4 < 64; c4++) {
        float4 w = wp[(size_t)c4 * 128];
        float4 p0 = xa[c4], p1 = xb4[c4];
        a0 += w.x * p0.x + w.y * p0.y + w.z * p0.z + w.w * p0.w;
        a1 += w.x * p1.x + w.y * p1.y + w.z * p1.z + w.w * p1.w;
    }
#pragma unroll
    for (int k = 0; k < 2; k++) {
        int pix = blk * 4 + ph * 2 + k;
        int b = pix / HW, p = pix - b * HW;
        float a = k ? a1 : a0;
        if (o < 64) {
            q_pix[(((size_t)b * HW) + p) * 64 + o] = a;
        } else {
            int t = o - 64, g = t >> 5, c32 = t & 31;
            k_nhwc[(((size_t)(b * 2 + g) * HW) + p) * 32 + c32] = a;
        }
    }
}

// ---------------- K3: t = GELU(LN(dw3x3(resize(q)))). Thread per (bg, pixel, ch).
// Wave = 2 pixels x 32 ch; LN via 32-lane-half shfl. No LDS.
__global__ __launch_bounds__(256) void k3_t(const float* __restrict__ q_pix,
                                            const float* __restrict__ dwT,
                                            const float* __restrict__ og,
                                            const float* __restrict__ ob,
                                            float* __restrict__ tbuf) {
    int gid = blockIdx.x * 256 + threadIdx.x;   // 4*9216*32
    int c = gid & 31;
    int p2 = gid >> 5;                          // bg*9216 + p
    int bg = p2 / N1, p = p2 - bg * N1;
    int b = bg >> 1, g = bg & 1;
    int oy = p / OW, ox = p - oy * OW;
    const float* qb = q_pix + ((size_t)b * HW) * 64 + g * 32 + c;
    float acc = 0.f;
#pragma unroll
    for (int dy = -1; dy <= 1; dy++) {
        int yy = oy + dy;
        if ((unsigned)yy >= (unsigned)OH) continue;
        float ysf = yy * RESZ;
        int y0 = min((int)ysf, 46);
        float wy = ysf - (float)y0;
#pragma unroll
        for (int dx = -1; dx <= 1; dx++) {
            int xx = ox + dx;
            if ((unsigned)xx >= (unsigned)OW) continue;
            float xsf = xx * RESZ;
            int x0 = min((int)xsf, 46);
            float wx = xsf - (float)x0;
            int i00 = (y0 * 48 + x0) * 64;
            float q00 = qb[i00], q01 = qb[i00 + 64];
            float q10 = qb[i00 + 48 * 64], q11 = qb[i00 + 49 * 64];
            float qv = (q00 * (1.f - wy) + q10 * wy) * (1.f - wx)
                     + (q01 * (1.f - wy) + q11 * wy) * wx;
            acc += qv * dwT[((dy + 1) * 3 + dx + 1) * 32 + c];
        }
    }
    // LN over the 32 channels (confined to each 32-lane half)
    float s = acc;
#pragma unroll
    for (int off = 1; off < 32; off <<= 1) s += __shfl_xor(s, off);
    float mu = s * (1.f / 32.f);
    float d = acc - mu;
    float v = d * d;
#pragma unroll
    for (int off = 1; off < 32; off <<= 1) v += __shfl_xor(v, off);
    float rsv = rsqrtf(v * (1.f / 32.f) + 1e-5f);
    float t = d * rsv * og[c] + ob[c];
    float ge = 0.5f * t * (1.f + erff(t * 0.70710678118654752f));
    tbuf[(size_t)p2 * 32 + c] = ge;
}

// ---------------- K4: conv 3x3 32->18 + bias. Thread per (bg, pixel, oc). No LDS.
// pred stored pixel-major [bg][p][18] -> store is pred[gid].
__global__ __launch_bounds__(256) void k4_pred(const float* __restrict__ tbuf,
                                               const float* __restrict__ wT2,
                                               const float* __restrict__ off_b,
                                               float* __restrict__ pred) {
    int gid = blockIdx.x * 256 + threadIdx.x;   // 4*9216*18
    if (gid >= 4 * N1 * 18) return;
    int p18 = gid / 18, oc = gid - p18 * 18;
    int bg = p18 / N1, p = p18 - bg * N1;
    int oy = p / OW, ox = p - oy * OW;
    const float* tb = tbuf + (size_t)bg * N1 * 32;
    int pn[9];
    bool vl[9];
#pragma unroll
    for (int dy = -1; dy <= 1; dy++)
#pragma unroll
        for (int dx = -1; dx <= 1; dx++) {
            int k = (dy + 1) * 3 + (dx + 1);
            vl[k] = ((unsigned)(oy + dy) < (unsigned)OH) && ((unsigned)(ox + dx) < (unsigned)OW);
            pn[k] = (p + dy * OW + dx) * 32;
        }
    float acc = off_b[oc];
    for (int ic = 0; ic < 32; ic++) {
#pragma unroll
        for (int k = 0; k < 9; k++) {
            if (vl[k]) acc += tb[pn[k] + ic] * wT2[(ic * 9 + k) * 18 + oc];
        }
    }
    pred[gid] = acc;
}

// ---------------- K2b: v (=x) NCHW -> NHWC per group via LDS tile: [4][2304][128]
__global__ void k2b_vt(const float* __restrict__ x, float* __restrict__ v_nhwc) {
    int blk = blockIdx.x;
    int pt = blk % 72;
    int t2 = blk / 72;
    int ct = t2 & 3;
    int bg = t2 >> 2;
    int b = bg >> 1, g = bg & 1;
    __shared__ float tile[32][33];
    int tx = threadIdx.x & 31, row = threadIdx.x >> 5;   // row 0..7
#pragma unroll
    for (int r = 0; r < 4; r++) {
        int c = ct * 32 + row + r * 8;
        tile[row + r * 8][tx] = x[((size_t)(b * 256 + g * 128 + c)) * HW + pt * 32 + tx];
    }
    __syncthreads();
#pragma unroll
    for (int r = 0; r < 4; r++) {
        int p = pt * 32 + row + r * 8;
        v_nhwc[((size_t)bg * HW + p) * 128 + ct * 32 + tx] = tile[tx][row + r * 8];
    }
}

// ---------------- K5: deformable attention. 1 wave = 4 consecutive pixels (same row);
// block = 16 pixels. q resized on the fly; softmax in-register; per-lane float4 v-loads.
__global__ __launch_bounds__(256) void k5_attn(const float* __restrict__ pred,
                                               const float* __restrict__ q_pix,
                                               const float* __restrict__ k_nhwc,
                                               const float* __restrict__ v_nhwc,
                                               const float* __restrict__ rpb,
                                               float* __restrict__ out) {
    int tid = threadIdx.x;
    int wv = __builtin_amdgcn_readfirstlane(tid >> 6);
    int lane = tid & 63;
    int gp = blockIdx.x * 16;              // block-base pixel (same bg, same row)
    int bg = gp / N1, p0 = gp % N1;
    int b = bg >> 1, g = bg & 1;
    int pw = p0 + wv * 4;                  // wave-base pixel
    int oy = pw / OW, ox0 = pw % OW;

    __shared__ float4 wts[4][4][9];        // [wave][px][tap] corner weights
    __shared__ int4   cof[4][4][9];        // [wave][px][tap] corner pixel offsets
    __shared__ float  outb[4][4][128];     // [wave][px][ch]

    // --- tap setup: lanes 0..35 -> (px, j)
    if (lane < 36) {
        int px = lane / 9, j = lane % 9;
        int p = pw + px;
        int ky = j / 3, kx = j % 3;
        const float* pp = pred + ((size_t)bg * N1 + p) * 18;
        float pr0 = pp[j * 2];
        float pr1 = pp[j * 2 + 1];
        float th0 = 1.f - 2.f * __builtin_amdgcn_rcpf(__expf(2.f * pr0) + 1.f);
        float th1 = 1.f - 2.f * __builtin_amdgcn_rcpf(__expf(2.f * pr1) + 1.f);
        float py  = th0 * 11.0f + (float)(ky - 1) + (float)oy;
        float pxc = th1 * 11.0f + (float)(kx - 1) + (float)(ox0 + px);
        float iy = py * RESZ, ix = pxc * RESZ;
        float y0f = floorf(iy), x0f = floorf(ix);
        float wy = iy - y0f, wx = ix - x0f;
        int y0 = (int)y0f, x0 = (int)x0f;
        bool vy0 = (unsigned)y0 < 48u, vy1 = (unsigned)(y0 + 1) < 48u;
        bool vx0 = (unsigned)x0 < 48u, vx1 = (unsigned)(x0 + 1) < 48u;
        int y0c = min(max(y0, 0), 47), y1c = min(max(y0 + 1, 0), 47);
        int x0c = min(max(x0, 0), 47), x1c = min(max(x0 + 1, 0), 47);
        float4 w;
        w.x = (vy0 && vx0) ? (1.f - wy) * (1.f - wx) : 0.f;
        w.y = (vy0 && vx1) ? (1.f - wy) * wx : 0.f;
        w.z = (vy1 && vx0) ? wy * (1.f - wx) : 0.f;
        w.w = (vy1 && vx1) ? wy * wx : 0.f;
        wts[wv][px][j] = w;
        cof[wv][px][j] = make_int4(y0c * 48 + x0c, y0c * 48 + x1c,
                                   y1c * 48 + x0c, y1c * 48 + x1c);
    }
    __syncthreads();

    int c = lane & 31, h = lane >> 5;
    int c4 = (lane & 31) * 4;
    const float* kb = k_nhwc + (size_t)bg * HW * 32;
    const float* rb = rpb + (size_t)g * 288;
    const float* qb = q_pix + (size_t)b * HW * 64 + g * 32 + c;
    const float* vbase = v_nhwc + (size_t)bg * HW * 128;

    float ysf = oy * RESZ;
    int qy0 = min((int)ysf, 46);
    float qwy = ysf - (float)qy0;

    for (int px = 0; px < 4; px++) {
        // on-the-fly resized q (lane c channel)
        float xsf = (ox0 + px) * RESZ;
        int qx0 = min((int)xsf, 46);
        float qwx = xsf - (float)qx0;
        int qi = (qy0 * 48 + qx0) * 64;
        float q00 = qb[qi], q01 = qb[qi + 64];
        float q10 = qb[qi + 48 * 64], q11 = qb[qi + 49 * 64];
        float qv = ((q00 * (1.f - qwy) + q10 * qwy) * (1.f - qwx)
                  + (q01 * (1.f - qwy) + q11 * qwy) * qwx) * SCALE_ATTN;

        // scores: h-split taps; after xor-reduce all 32 lanes of a half hold the sum
        float s[5], e[5];
#pragma unroll
        for (int jj = 0; jj < 5; jj++) {
            int j = jj * 2 + h;
            float partial = 0.f;
            if (j < 9) {
                float4 w = wts[wv][px][j];
                int4 co = cof[wv][px][j];
                float kv = w.x * kb[co.x * 32 + c] + w.y * kb[co.y * 32 + c]
                         + w.z * kb[co.z * 32 + c] + w.w * kb[co.w * 32 + c];
                partial = qv * (kv + rb[j * 32 + c]);
            }
#pragma unroll
            for (int off = 1; off < 32; off <<= 1) partial += __shfl_xor(partial, off);
            s[jj] = (j < 9) ? partial : -1e30f;
        }
        // in-register softmax across both halves
        float m = s[0];
#pragma unroll
        for (int jj = 1; jj < 5; jj++) m = fmaxf(m, s[jj]);
        m = fmaxf(m, __shfl_xor(m, 32));
        float sum = 0.f;
#pragma unroll
        for (int jj = 0; jj < 5; jj++) { e[jj] = __expf(s[jj] - m); sum += e[jj]; }
        sum += __shfl_xor(sum, 32);
        float inv = __builtin_amdgcn_rcpf(sum);

        // value phase: float4 per lane over 128 ch, h-split taps
        float4 acc = make_float4(0.f, 0.f, 0.f, 0.f);
#pragma unroll
        for (int jj = 0; jj < 5; jj++) {
            int j = jj * 2 + h;
            if (j < 9) {
                float pj = e[jj] * inv;
                float4 w = wts[wv][px][j];
                int4 co = cof[wv][px][j];
                float4 a0 = *(const float4*)(vbase + (size_t)co.x * 128 + c4);
                float4 a1 = *(const float4*)(vbase + (size_t)co.y * 128 + c4);
                float4 a2 = *(const float4*)(vbase + (size_t)co.z * 128 + c4);
                float4 a3 = *(const float4*)(vbase + (size_t)co.w * 128 + c4);
                float f0 = w.x * pj, f1 = w.y * pj, f2 = w.z * pj, f3 = w.w * pj;
                acc.x += f0 * a0.x + f1 * a1.x + f2 * a2.x + f3 * a3.x;
                acc.y += f0 * a0.y + f1 * a1.y + f2 * a2.y + f3 * a3.y;
                acc.z += f0 * a0.z + f1 * a1.z + f2 * a2.z + f3 * a3.z;
                acc.w += f0 * a0.w + f1 * a1.w + f2 * a2.w + f3 * a3.w;
            }
        }
        acc.x += __shfl_xor(acc.x, 32);
        acc.y += __shfl_xor(acc.y, 32);
        acc.z += __shfl_xor(acc.z, 32);
        acc.w += __shfl_xor(acc.w, 32);
        if (lane < 32) *(float4*)&outb[wv][px][c4] = acc;
    }
    __syncthreads();

    // final write: thread ch<128 writes 4x float4 = 64B contiguous per channel
    if (tid < 128) {
        int ch = tid;
        float* op = out + ((size_t)b * NC + g * 128 + ch) * N1 + p0;
#pragma unroll
        for (int w2 = 0; w2 < 4; w2++) {
            float4 v4 = make_float4(outb[w2][0][ch], outb[w2][1][ch],
                                    outb[w2][2][ch], outb[w2][3][ch]);
            *(float4*)(op + w2 * 4) = v4;
        }
    }
}

extern "C" void kernel_launch(void* const* d_in, const int* in_sizes, int n_in,
                              void* d_out, int out_size, void* d_ws, size_t ws_size,
                              hipStream_t stream) {
    const float* x      = (const float*)d_in[0];
    const float* ln_g   = (const float*)d_in[1];
    const float* ln_b   = (const float*)d_in[2];
    const float* Wq     = (const float*)d_in[3];
    const float* Wk     = (const float*)d_in[4];
    const float* dw_w   = (const float*)d_in[5];
    const float* off_g  = (const float*)d_in[6];
    const float* off_bt = (const float*)d_in[7];
    const float* off_w  = (const float*)d_in[8];
    const float* off_b  = (const float*)d_in[9];
    const float* rpb    = (const float*)d_in[10];
    float* out = (float*)d_out;

    // Workspace layout (floats). Total = 2,471,264 floats = 9.43 MB.
    // U is time-shared: tbuf (k3->k4) then v_nhwc (k2b->k5).
    float* ws = (float*)d_ws;
    float* U      = ws;                       // 1179648
    float* tbuf   = U;                        // [4][9216][32]
    float* v_nhwc = U;                        // [4][2304][128]
    float* WT4    = U + 1179648;              // 32768   [64][128][4]
    float* k_nhwc = WT4 + 32768;              // 294912  [4][2304][32]
    float* q_pix  = k_nhwc + 294912;          // 294912  [2][2304][64]
    float* pred   = q_pix + 294912;           // 663552  [4][9216][18]
    float* wT2    = pred + 663552;            // 5184    [288][18]
    float* dwT    = wT2 + 5184;               // 288     [9][32]

    kA_prep<<<150, 256, 0, stream>>>(Wq, Wk, off_w, dw_w, WT4, wT2, dwT);
    k1_ln_qk<<<1152, 256, 0, stream>>>(x, ln_g, ln_b, WT4, q_pix, k_nhwc);
    k3_t<<<4608, 256, 0, stream>>>(q_pix, dwT, off_g, off_bt, tbuf);
    k4_pred<<<2592, 256, 0, stream>>>(tbuf, wT2, off_b, pred);
    k2b_vt<<<1152, 256, 0, stream>>>(x, v_nhwc);
    k5_attn<<<2304, 256, 0, stream>>>(pred, q_pix, k_nhwc, v_nhwc, rpb, out);
}

// Round 9
// 175.726 us; speedup vs baseline: 2.0289x; 2.0289x over previous
//
#include <hip/hip_runtime.h>
#include <cstdint>
#include <cmath>

// Problem constants
#define NB 2
#define NC 256
#define HW 2304          // 48*48
#define HID 64
#define OH 96
#define OW 96
#define N1 9216          // 96*96
#define SCALE_ATTN 0.17677669529663689f   // 32^-0.5
#define RESZ ((float)(47.0/95.0))

// oc-group split for k4: waves {0,1} take 5 ocs, {2,3} take 4
__device__ __host__ inline int ocb_of(int w) { return w < 2 ? w * 5 : 10 + (w - 2) * 4; }
__device__ __host__ inline int cnt_of(int w) { return w < 2 ? 5 : 4; }

// ---------------- KA: weight prep.
// WT4[c4][128][4]; dwT[tap][32]; wg[4][288][5] (zero-padded oc-groups); bsg[20]
__global__ void kA_prep(const float* __restrict__ Wq, const float* __restrict__ Wk,
                        const float* __restrict__ off_w, const float* __restrict__ dw_w,
                        const float* __restrict__ off_b,
                        float* __restrict__ WT4, float* __restrict__ dwT,
                        float* __restrict__ wg, float* __restrict__ bsg) {
    int idx = blockIdx.x * 256 + threadIdx.x;
    if (idx < 256 * 128) {
        int c = idx >> 7, t = idx & 127;
        float v = (t < 64) ? Wq[t * 256 + c] : Wk[(t - 64) * 256 + c];
        WT4[(((size_t)(c >> 2) * 128) + t) * 4 + (c & 3)] = v;
    } else if (idx < 256 * 128 + 288) {
        int i = idx - 256 * 128;
        int wi = i >> 5, c = i & 31;
        dwT[i] = dw_w[c * 9 + wi];
    } else if (idx < 256 * 128 + 288 + 4 * 288 * 5) {
        int i = idx - (256 * 128 + 288);
        int w = i / 1440, r = i - w * 1440;
        int kk = r / 5, j = r - kk * 5;
        wg[i] = (j < cnt_of(w)) ? off_w[(ocb_of(w) + j) * 288 + kk] : 0.f;
    } else if (idx < 256 * 128 + 288 + 4 * 288 * 5 + 20) {
        int i = idx - (256 * 128 + 288 + 4 * 288 * 5);
        int w = i / 5, j = i - w * 5;
        bsg[i] = (j < cnt_of(w)) ? off_b[ocb_of(w) + j] : 0.f;
    }
}

// ---------------- K1: channel LN over 256 + Q/K projection, reading x directly.
__global__ __launch_bounds__(256) void k1_ln_qk(const float* __restrict__ x,
                         const float* __restrict__ ln_g, const float* __restrict__ ln_b,
                         const float* __restrict__ WT4,
                         float* __restrict__ q_pix, float* __restrict__ k_nhwc) {
    int blk = blockIdx.x;            // 0..1151
    int tid = threadIdx.x;
    int wv = tid >> 6, lane = tid & 63;
    __shared__ float xs[4][256];
    {
        int pix = blk * 4 + wv;
        int b = pix / HW, p = pix - b * HW;
        const float* xb = x + (size_t)b * NC * HW + p;
        float v0 = xb[(size_t)lane * HW];
        float v1 = xb[(size_t)(lane + 64) * HW];
        float v2 = xb[(size_t)(lane + 128) * HW];
        float v3 = xb[(size_t)(lane + 192) * HW];
        float s = v0 + v1 + v2 + v3;
#pragma unroll
        for (int off = 1; off < 64; off <<= 1) s += __shfl_xor(s, off);
        float mu = s * (1.f / 256.f);
        float d0 = v0 - mu, d1 = v1 - mu, d2 = v2 - mu, d3 = v3 - mu;
        float q = d0 * d0 + d1 * d1 + d2 * d2 + d3 * d3;
#pragma unroll
        for (int off = 1; off < 64; off <<= 1) q += __shfl_xor(q, off);
        float rs = rsqrtf(q * (1.f / 256.f) + 1e-5f);
        xs[wv][lane]       = d0 * rs * ln_g[lane]       + ln_b[lane];
        xs[wv][lane + 64]  = d1 * rs * ln_g[lane + 64]  + ln_b[lane + 64];
        xs[wv][lane + 128] = d2 * rs * ln_g[lane + 128] + ln_b[lane + 128];
        xs[wv][lane + 192] = d3 * rs * ln_g[lane + 192] + ln_b[lane + 192];
    }
    __syncthreads();
    int o = tid & 127, ph = tid >> 7;
    float a0 = 0.f, a1 = 0.f;
    const float4* wp = (const float4*)WT4 + o;         // stride 128 float4s per c4
    const float4* xa = (const float4*)xs[ph * 2];
    const float4* xb4 = (const float4*)xs[ph * 2 + 1];
#pragma unroll 8
    for (int c4 = 0; c4 < 64; c4++) {
        float4 w = wp[(size_t)c4 * 128];
        float4 p0 = xa[c4], p1 = xb4[c4];
        a0 += w.x * p0.x + w.y * p0.y + w.z * p0.z + w.w * p0.w;
        a1 += w.x * p1.x + w.y * p1.y + w.z * p1.z + w.w * p1.w;
    }
#pragma unroll
    for (int k = 0; k < 2; k++) {
        int pix = blk * 4 + ph * 2 + k;
        int b = pix / HW, p = pix - b * HW;
        float a = k ? a1 : a0;
        if (o < 64) {
            q_pix[(((size_t)b * HW) + p) * 64 + o] = a;
        } else {
            int t = o - 64, g = t >> 5, c32 = t & 31;
            k_nhwc[(((size_t)(b * 2 + g) * HW) + p) * 32 + c32] = a;
        }
    }
}

// ---------------- K3: t = GELU(LN(dw3x3(resize(q)))). Thread per (bg, pixel, ch).
__global__ __launch_bounds__(256) void k3_t(const float* __restrict__ q_pix,
                                            const float* __restrict__ dwT,
                                            const float* __restrict__ og,
                                            const float* __restrict__ ob,
                                            float* __restrict__ tbuf) {
    int gid = blockIdx.x * 256 + threadIdx.x;   // 4*9216*32
    int c = gid & 31;
    int p2 = gid >> 5;                          // bg*9216 + p
    int bg = p2 / N1, p = p2 - bg * N1;
    int b = bg >> 1, g = bg & 1;
    int oy = p / OW, ox = p - oy * OW;
    const float* qb = q_pix + ((size_t)b * HW) * 64 + g * 32 + c;
    float acc = 0.f;
#pragma unroll
    for (int dy = -1; dy <= 1; dy++) {
        int yy = oy + dy;
        if ((unsigned)yy >= (unsigned)OH) continue;
        float ysf = yy * RESZ;
        int y0 = min((int)ysf, 46);
        float wy = ysf - (float)y0;
#pragma unroll
        for (int dx = -1; dx <= 1; dx++) {
            int xx = ox + dx;
            if ((unsigned)xx >= (unsigned)OW) continue;
            float xsf = xx * RESZ;
            int x0 = min((int)xsf, 46);
            float wx = xsf - (float)x0;
            int i00 = (y0 * 48 + x0) * 64;
            float q00 = qb[i00], q01 = qb[i00 + 64];
            float q10 = qb[i00 + 48 * 64], q11 = qb[i00 + 49 * 64];
            float qv = (q00 * (1.f - wy) + q10 * wy) * (1.f - wx)
                     + (q01 * (1.f - wy) + q11 * wy) * wx;
            acc += qv * dwT[((dy + 1) * 3 + dx + 1) * 32 + c];
        }
    }
    // LN over the 32 channels (confined to each 32-lane half)
    float s = acc;
#pragma unroll
    for (int off = 1; off < 32; off <<= 1) s += __shfl_xor(s, off);
    float mu = s * (1.f / 32.f);
    float d = acc - mu;
    float v = d * d;
#pragma unroll
    for (int off = 1; off < 32; off <<= 1) v += __shfl_xor(v, off);
    float rsv = rsqrtf(v * (1.f / 32.f) + 1e-5f);
    float t = d * rsv * og[c] + ob[c];
    float ge = 0.5f * t * (1.f + erff(t * 0.70710678118654752f));
    tbuf[(size_t)p2 * 32 + c] = ge;
}

// ---------------- K4: conv 3x3 32->18 + bias.
// Grid: 4 bg x 144 tiles (8x8 px) = 576 blocks. Stage 10x10 halo x 32ch in LDS (pitch 33).
// Wave w owns oc-group (5/5/4/4); lane = pixel; weights wave-uniform from wg.
__global__ __launch_bounds__(256) void k4_pred(const float* __restrict__ tbuf,
                                               const float* __restrict__ wg,
                                               const float* __restrict__ bsg,
                                               float* __restrict__ pred) {
    int blk = blockIdx.x;
    int bg = blk / 144, tile = blk - bg * 144;
    int ty0 = (tile / 12) * 8, tx0 = (tile % 12) * 8;
    int tid = threadIdx.x;
    __shared__ float ts[100 * 33];   // [halo point][ic], pitch 33

    const float* tb = tbuf + (size_t)bg * N1 * 32;
    for (int item = tid; item < 800; item += 256) {
        int pt = item >> 3, q = item & 7;
        int hy = ty0 + pt / 10 - 1;
        int hx = tx0 + pt % 10 - 1;
        float4 v = make_float4(0.f, 0.f, 0.f, 0.f);
        if ((unsigned)hy < (unsigned)OH && (unsigned)hx < (unsigned)OW)
            v = *(const float4*)(tb + ((size_t)(hy * OW + hx)) * 32 + q * 4);
        int base = pt * 33 + q * 4;
        ts[base] = v.x; ts[base + 1] = v.y; ts[base + 2] = v.z; ts[base + 3] = v.w;
    }
    __syncthreads();

    int w = __builtin_amdgcn_readfirstlane(tid >> 6);
    int lane = tid & 63;
    int y = lane >> 3, x = lane & 7;
    int ocb = ocb_of(w), cnt = cnt_of(w);
    float acc[5];
#pragma unroll
    for (int j = 0; j < 5; j++) acc[j] = bsg[w * 5 + j];
    const float* tsb = &ts[(y * 10 + x) * 33];
    const float* wgp = wg + (size_t)w * 1440;
    const int kof[9] = {0, 33, 66, 330, 363, 396, 660, 693, 726};
    for (int ic = 0; ic < 32; ic++) {
#pragma unroll
        for (int k = 0; k < 9; k++) {
            float tv = tsb[kof[k] + ic];
            const float* wr = wgp + (ic * 9 + k) * 5;
#pragma unroll
            for (int j = 0; j < 5; j++) acc[j] += tv * wr[j];
        }
    }
    int p = (ty0 + y) * OW + tx0 + x;
    float* pp = pred + ((size_t)bg * N1 + p) * 18 + ocb;
#pragma unroll
    for (int j = 0; j < 5; j++)
        if (j < cnt) pp[j] = acc[j];
}

// ---------------- K2b: v (=x) NCHW -> NHWC per group via LDS tile: [4][2304][128]
__global__ void k2b_vt(const float* __restrict__ x, float* __restrict__ v_nhwc) {
    int blk = blockIdx.x;
    int pt = blk % 72;
    int t2 = blk / 72;
    int ct = t2 & 3;
    int bg = t2 >> 2;
    int b = bg >> 1, g = bg & 1;
    __shared__ float tile[32][33];
    int tx = threadIdx.x & 31, row = threadIdx.x >> 5;   // row 0..7
#pragma unroll
    for (int r = 0; r < 4; r++) {
        int c = ct * 32 + row + r * 8;
        tile[row + r * 8][tx] = x[((size_t)(b * 256 + g * 128 + c)) * HW + pt * 32 + tx];
    }
    __syncthreads();
#pragma unroll
    for (int r = 0; r < 4; r++) {
        int p = pt * 32 + row + r * 8;
        v_nhwc[((size_t)bg * HW + p) * 128 + ct * 32 + tx] = tile[tx][row + r * 8];
    }
}

// ---------------- K5: deformable attention. 1 wave = 4 consecutive pixels (same row);
// block = 16 pixels. q resized on the fly; softmax in-register; per-lane float4 v-loads.
__global__ __launch_bounds__(256) void k5_attn(const float* __restrict__ pred,
                                               const float* __restrict__ q_pix,
                                               const float* __restrict__ k_nhwc,
                                               const float* __restrict__ v_nhwc,
                                               const float* __restrict__ rpb,
                                               float* __restrict__ out) {
    int tid = threadIdx.x;
    int wv = __builtin_amdgcn_readfirstlane(tid >> 6);
    int lane = tid & 63;
    int gp = blockIdx.x * 16;              // block-base pixel (same bg, same row)
    int bg = gp / N1, p0 = gp % N1;
    int b = bg >> 1, g = bg & 1;
    int pw = p0 + wv * 4;                  // wave-base pixel
    int oy = pw / OW, ox0 = pw % OW;

    __shared__ float4 wts[4][4][9];        // [wave][px][tap] corner weights
    __shared__ int4   cof[4][4][9];        // [wave][px][tap] corner pixel offsets
    __shared__ float  outb[4][4][128];     // [wave][px][ch]

    // --- tap setup: lanes 0..35 -> (px, j)
    if (lane < 36) {
        int px = lane / 9, j = lane % 9;
        int p = pw + px;
        int ky = j / 3, kx = j % 3;
        const float* pp = pred + ((size_t)bg * N1 + p) * 18;
        float pr0 = pp[j * 2];
        float pr1 = pp[j * 2 + 1];
        float th0 = 1.f - 2.f * __builtin_amdgcn_rcpf(__expf(2.f * pr0) + 1.f);
        float th1 = 1.f - 2.f * __builtin_amdgcn_rcpf(__expf(2.f * pr1) + 1.f);
        float py  = th0 * 11.0f + (float)(ky - 1) + (float)oy;
        float pxc = th1 * 11.0f + (float)(kx - 1) + (float)(ox0 + px);
        float iy = py * RESZ, ix = pxc * RESZ;
        float y0f = floorf(iy), x0f = floorf(ix);
        float wy = iy - y0f, wx = ix - x0f;
        int y0 = (int)y0f, x0 = (int)x0f;
        bool vy0 = (unsigned)y0 < 48u, vy1 = (unsigned)(y0 + 1) < 48u;
        bool vx0 = (unsigned)x0 < 48u, vx1 = (unsigned)(x0 + 1) < 48u;
        int y0c = min(max(y0, 0), 47), y1c = min(max(y0 + 1, 0), 47);
        int x0c = min(max(x0, 0), 47), x1c = min(max(x0 + 1, 0), 47);
        float4 w;
        w.x = (vy0 && vx0) ? (1.f - wy) * (1.f - wx) : 0.f;
        w.y = (vy0 && vx1) ? (1.f - wy) * wx : 0.f;
        w.z = (vy1 && vx0) ? wy * (1.f - wx) : 0.f;
        w.w = (vy1 && vx1) ? wy * wx : 0.f;
        wts[wv][px][j] = w;
        cof[wv][px][j] = make_int4(y0c * 48 + x0c, y0c * 48 + x1c,
                                   y1c * 48 + x0c, y1c * 48 + x1c);
    }
    __syncthreads();

    int c = lane & 31, h = lane >> 5;
    int c4 = (lane & 31) * 4;
    const float* kb = k_nhwc + (size_t)bg * HW * 32;
    const float* rb = rpb + (size_t)g * 288;
    const float* qb = q_pix + (size_t)b * HW * 64 + g * 32 + c;
    const float* vbase = v_nhwc + (size_t)bg * HW * 128;

    float ysf = oy * RESZ;
    int qy0 = min((int)ysf, 46);
    float qwy = ysf - (float)qy0;

    for (int px = 0; px < 4; px++) {
        // on-the-fly resized q (lane c channel)
        float xsf = (ox0 + px) * RESZ;
        int qx0 = min((int)xsf, 46);
        float qwx = xsf - (float)qx0;
        int qi = (qy0 * 48 + qx0) * 64;
        float q00 = qb[qi], q01 = qb[qi + 64];
        float q10 = qb[qi + 48 * 64], q11 = qb[qi + 49 * 64];
        float qv = ((q00 * (1.f - qwy) + q10 * qwy) * (1.f - qwx)
                  + (q01 * (1.f - qwy) + q11 * qwy) * qwx) * SCALE_ATTN;

        // scores: h-split taps; after xor-reduce all 32 lanes of a half hold the sum
        float s[5], e[5];
#pragma unroll
        for (int jj = 0; jj < 5; jj++) {
            int j = jj * 2 + h;
            float partial = 0.f;
            if (j < 9) {
                float4 w = wts[wv][px][j];
                int4 co = cof[wv][px][j];
                float kv = w.x * kb[co.x * 32 + c] + w.y * kb[co.y * 32 + c]
                         + w.z * kb[co.z * 32 + c] + w.w * kb[co.w * 32 + c];
                partial = qv * (kv + rb[j * 32 + c]);
            }
#pragma unroll
            for (int off = 1; off < 32; off <<= 1) partial += __shfl_xor(partial, off);
            s[jj] = (j < 9) ? partial : -1e30f;
        }
        // in-register softmax across both halves
        float m = s[0];
#pragma unroll
        for (int jj = 1; jj < 5; jj++) m = fmaxf(m, s[jj]);
        m = fmaxf(m, __shfl_xor(m, 32));
        float sum = 0.f;
#pragma unroll
        for (int jj = 0; jj < 5; jj++) { e[jj] = __expf(s[jj] - m); sum += e[jj]; }
        sum += __shfl_xor(sum, 32);
        float inv = __builtin_amdgcn_rcpf(sum);

        // value phase: float4 per lane over 128 ch, h-split taps
        float4 acc = make_float4(0.f, 0.f, 0.f, 0.f);
#pragma unroll
        for (int jj = 0; jj < 5; jj++) {
            int j = jj * 2 + h;
            if (j < 9) {
                float pj = e[jj] * inv;
                float4 w = wts[wv][px][j];
                int4 co = cof[wv][px][j];
                float4 a0 = *(const float4*)(vbase + (size_t)co.x * 128 + c4);
                float4 a1 = *(const float4*)(vbase + (size_t)co.y * 128 + c4);
                float4 a2 = *(const float4*)(vbase + (size_t)co.z * 128 + c4);
                float4 a3 = *(const float4*)(vbase + (size_t)co.w * 128 + c4);
                float f0 = w.x * pj, f1 = w.y * pj, f2 = w.z * pj, f3 = w.w * pj;
                acc.x += f0 * a0.x + f1 * a1.x + f2 * a2.x + f3 * a3.x;
                acc.y += f0 * a0.y + f1 * a1.y + f2 * a2.y + f3 * a3.y;
                acc.z += f0 * a0.z + f1 * a1.z + f2 * a2.z + f3 * a3.z;
                acc.w += f0 * a0.w + f1 * a1.w + f2 * a2.w + f3 * a3.w;
            }
        }
        acc.x += __shfl_xor(acc.x, 32);
        acc.y += __shfl_xor(acc.y, 32);
        acc.z += __shfl_xor(acc.z, 32);
        acc.w += __shfl_xor(acc.w, 32);
        if (lane < 32) *(float4*)&outb[wv][px][c4] = acc;
    }
    __syncthreads();

    // final write: thread ch<128 writes 4x float4 = 64B contiguous per channel
    if (tid < 128) {
        int ch = tid;
        float* op = out + ((size_t)b * NC + g * 128 + ch) * N1 + p0;
#pragma unroll
        for (int w2 = 0; w2 < 4; w2++) {
            float4 v4 = make_float4(outb[w2][0][ch], outb[w2][1][ch],
                                    outb[w2][2][ch], outb[w2][3][ch]);
            *(float4*)(op + w2 * 4) = v4;
        }
    }
}

extern "C" void kernel_launch(void* const* d_in, const int* in_sizes, int n_in,
                              void* d_out, int out_size, void* d_ws, size_t ws_size,
                              hipStream_t stream) {
    const float* x      = (const float*)d_in[0];
    const float* ln_g   = (const float*)d_in[1];
    const float* ln_b   = (const float*)d_in[2];
    const float* Wq     = (const float*)d_in[3];
    const float* Wk     = (const float*)d_in[4];
    const float* dw_w   = (const float*)d_in[5];
    const float* off_g  = (const float*)d_in[6];
    const float* off_bt = (const float*)d_in[7];
    const float* off_w  = (const float*)d_in[8];
    const float* off_b  = (const float*)d_in[9];
    const float* rpb    = (const float*)d_in[10];
    float* out = (float*)d_out;

    // Workspace layout (floats). Total = 2,471,828 floats = 9.43 MB.
    // U is time-shared: tbuf (k3->k4) then v_nhwc (k2b->k5).
    float* ws = (float*)d_ws;
    float* U      = ws;                       // 1179648
    float* tbuf   = U;                        // [4][9216][32]
    float* v_nhwc = U;                        // [4][2304][128]
    float* WT4    = U + 1179648;              // 32768   [64][128][4]
    float* k_nhwc = WT4 + 32768;              // 294912  [4][2304][32]
    float* q_pix  = k_nhwc + 294912;          // 294912  [2][2304][64]
    float* pred   = q_pix + 294912;           // 663552  [4][9216][18]
    float* dwT    = pred + 663552;            // 288     [9][32]
    float* wg     = dwT + 288;                // 5760    [4][288][5]
    float* bsg    = wg + 5760;                // 20      [4][5]

    kA_prep<<<173, 256, 0, stream>>>(Wq, Wk, off_w, dw_w, off_b, WT4, dwT, wg, bsg);
    k1_ln_qk<<<1152, 256, 0, stream>>>(x, ln_g, ln_b, WT4, q_pix, k_nhwc);
    k3_t<<<4608, 256, 0, stream>>>(q_pix, dwT, off_g, off_bt, tbuf);
    k4_pred<<<576, 256, 0, stream>>>(tbuf, wg, bsg, pred);   // 4 bg x 144 tiles
    k2b_vt<<<1152, 256, 0, stream>>>(x, v_nhwc);
    k5_attn<<<2304, 256, 0, stream>>>(pred, q_pix, k_nhwc, v_nhwc, rpb, out);
}